// Round 9
// baseline (386.324 us; speedup 1.0000x reference)
//
#include <hip/hip_runtime.h>
#include <hip/hip_bf16.h>

// GIN: 3x fused [CSR gather-sum + MLP(64->64->64) + relu] + pooled epilogue + linear
// x -> bf16 once; gathers bf16 with 8-way ILP, f32 accumulate.
// CSR: 391-bucket binning (packed pairs) + per-bucket counting sort.
// layer_kernel: per wave, aggregate 16 nodes -> LDS tile -> MFMA MLP;
// POOL=1 (layer 3) reduces rows into gsum atomics instead of storing.

#define N_NODES 100000
#define N_EDGES 1200000
#define N_GRAPH 128
#define N_CLS   10
#define NBUCK   391        // dst >> 8
#define BCAP    4096       // per-bucket capacity (mean 3070, +18 sigma)
#define BSH     12         // log2(BCAP)

typedef __bf16 bf16_t;
typedef __bf16 bf16x8 __attribute__((ext_vector_type(8)));
typedef float  f32x4  __attribute__((ext_vector_type(4)));

// ---------------- x -> bf16 ----------------
__global__ void tobf_kernel(const float* __restrict__ x, bf16_t* __restrict__ xb) {
    const int i = (blockIdx.x * 256 + threadIdx.x) * 8;
    const f32x4 a = *(const f32x4*)(x + i);
    const f32x4 b = *(const f32x4*)(x + i + 4);
    bf16x8 o;
#pragma unroll
    for (int j = 0; j < 4; ++j) { o[j] = (bf16_t)a[j]; o[4 + j] = (bf16_t)b[j]; }
    *(bf16x8*)(xb + i) = o;
}

// ---------------- CSR build ----------------
__global__ void binA_kernel(const int* __restrict__ ei,
                            int* __restrict__ bcnt,
                            int* __restrict__ bpair) {
    __shared__ int lcnt[NBUCK];
    __shared__ int lbase[NBUCK];
    const int t = threadIdx.x;
    for (int b = t; b < NBUCK; b += 256) lcnt[b] = 0;
    __syncthreads();
    const int e0 = (blockIdx.x * 256 + t) * 4;
    int4 s4, d4; int b[4], r[4];
    const bool valid = e0 < N_EDGES;               // N_EDGES % 4 == 0
    if (valid) {
        s4 = *(const int4*)(ei + e0);
        d4 = *(const int4*)(ei + N_EDGES + e0);
        b[0] = d4.x >> 8; b[1] = d4.y >> 8; b[2] = d4.z >> 8; b[3] = d4.w >> 8;
        r[0] = atomicAdd(&lcnt[b[0]], 1);
        r[1] = atomicAdd(&lcnt[b[1]], 1);
        r[2] = atomicAdd(&lcnt[b[2]], 1);
        r[3] = atomicAdd(&lcnt[b[3]], 1);
    }
    __syncthreads();
    for (int bb = t; bb < NBUCK; bb += 256) {
        const int c = lcnt[bb];
        lbase[bb] = c ? atomicAdd(&bcnt[bb], c) : 0;
    }
    __syncthreads();
    if (valid) {
        const int ss[4] = {s4.x, s4.y, s4.z, s4.w};
        const int dd[4] = {d4.x, d4.y, d4.z, d4.w};
#pragma unroll
        for (int j = 0; j < 4; ++j) {
            const int slot = lbase[b[j]] + r[j];
            if (slot < BCAP)
                bpair[(b[j] << BSH) + slot] = (ss[j] << 8) | (dd[j] & 255);
        }
    }
}

__global__ void bscan_kernel(const int* __restrict__ bcnt, int* __restrict__ cbase,
                             int* __restrict__ offset) {
    __shared__ int l[512];
    const int t = threadIdx.x;
    const int v = (t < NBUCK) ? bcnt[t] : 0;
    l[t] = v;
    __syncthreads();
    for (int d = 1; d < 512; d <<= 1) {
        int u = l[t];
        if (t >= d) u += l[t - d];
        __syncthreads();
        l[t] = u;
        __syncthreads();
    }
    if (t < NBUCK) cbase[t] = l[t] - v;
    if (t == NBUCK - 1) offset[N_NODES] = l[t];
}

__global__ void sortfill_kernel(const int* __restrict__ bpair,
                                const int* __restrict__ bcnt,
                                const int* __restrict__ cbase,
                                int* __restrict__ offset, int* __restrict__ csr) {
    __shared__ int hist[256];
    __shared__ int l[256];
    __shared__ int cursor[256];
    const int b = blockIdx.x;
    const int t = threadIdx.x;
    const int base = b << BSH;
    int cnt = bcnt[b];
    cnt = cnt < BCAP ? cnt : BCAP;

    hist[t] = 0;
    __syncthreads();
    for (int i = t; i < cnt; i += 256)
        atomicAdd(&hist[bpair[base + i] & 255], 1);
    __syncthreads();

    const int v = hist[t];
    l[t] = v;
    __syncthreads();
    for (int d = 1; d < 256; d <<= 1) {
        int u = l[t];
        if (t >= d) u += l[t - d];
        __syncthreads();
        l[t] = u;
        __syncthreads();
    }
    const int gpos = cbase[b] + l[t] - v;           // exclusive
    const int node = (b << 8) + t;
    if (node < N_NODES) offset[node] = gpos;
    cursor[t] = gpos;
    __syncthreads();

    for (int i = t; i < cnt; i += 256) {
        const int p = bpair[base + i];
        const int pos = atomicAdd(&cursor[p & 255], 1);
        csr[pos] = p >> 8;
    }
}

// ---------------------------------------------------------------------------
// Fused layer: per wave, aggregate 16 node rows (lane=feature, 8-way ILP
// gather) into LDS, then MFMA MLP. POOL=0: store bf16 rows; POOL=1: segmented
// reduce rows into gsum (mean-pool numerator) via one atomic per graph run.
// MFMA layouts: A[m=lane&15][k=quad*8+j]; B[k][n=ct*16+l15];
// C/D: row=quad*4+r, col=lane&15.
// ---------------------------------------------------------------------------
template <int POOL>
__global__ void layer_kernel(const bf16_t* __restrict__ xin,
                             const int* __restrict__ offset,
                             const int* __restrict__ csr,
                             const float* __restrict__ wa, const float* __restrict__ ba,
                             const float* __restrict__ wb, const float* __restrict__ bb,
                             bf16_t* __restrict__ xout,
                             const int* __restrict__ batch,
                             float* __restrict__ gsum) {
    __shared__ __align__(16) bf16_t wfrag[2][8][64][8];  // [mat][ct*2+ks][lane][j]
    __shared__ __align__(16) bf16_t hs[4][16][72];       // per-wave tile (agg/h1/h2)
    __shared__ float biasA[64], biasB[64];

    const int tid  = threadIdx.x;
    const int wv   = tid >> 6;
    const int lane = tid & 63;
    const int l15  = lane & 15;
    const int quad = lane >> 4;

    // ---- stage weights once per block ----
    {
        const int k  = tid >> 2;
        const int n0 = (tid & 3) << 4;
        const int ks = k >> 5, qd = (k >> 3) & 3, jj = k & 7;
        const int fi = ((n0 >> 4) << 1) + ks;
#pragma unroll
        for (int m = 0; m < 2; ++m) {
            const float* w = m ? wb : wa;
            const f32x4 v0 = *(const f32x4*)(w + k * 64 + n0);
            const f32x4 v1 = *(const f32x4*)(w + k * 64 + n0 + 4);
            const f32x4 v2 = *(const f32x4*)(w + k * 64 + n0 + 8);
            const f32x4 v3 = *(const f32x4*)(w + k * 64 + n0 + 12);
#pragma unroll
            for (int l = 0; l < 4; ++l) {
                wfrag[m][fi][qd * 16 + l][jj]      = (bf16_t)v0[l];
                wfrag[m][fi][qd * 16 + 4 + l][jj]  = (bf16_t)v1[l];
                wfrag[m][fi][qd * 16 + 8 + l][jj]  = (bf16_t)v2[l];
                wfrag[m][fi][qd * 16 + 12 + l][jj] = (bf16_t)v3[l];
            }
        }
        if (tid < 64) biasA[tid] = ba[tid];
        else if (tid < 128) biasB[tid - 64] = bb[tid - 64];
    }
    __syncthreads();

    const int rb = blockIdx.x * 64 + wv * 16;    // this wave's row base

    // ---- aggregate 16 rows into hs (lane = feature) ----
    for (int m = 0; m < 16; ++m) {
        const int row = rb + m;
        const int node = row < N_NODES ? row : N_NODES - 1;
        const int o0 = offset[node];
        const int o1 = offset[node + 1];
        float acc = (float)xin[node * 64 + lane];
        for (int i = o0; i < o1; i += 64) {
            const int cnt = (o1 - i < 64) ? (o1 - i) : 64;
            int s = 0;
            if (i + lane < o1) s = csr[i + lane];
            int j = 0;
            for (; j + 8 <= cnt; j += 8) {
                const int s0 = __shfl(s, j + 0), s1 = __shfl(s, j + 1);
                const int s2 = __shfl(s, j + 2), s3 = __shfl(s, j + 3);
                const int s4 = __shfl(s, j + 4), s5 = __shfl(s, j + 5);
                const int s6 = __shfl(s, j + 6), s7 = __shfl(s, j + 7);
                const float v0 = (float)xin[s0 * 64 + lane], v1 = (float)xin[s1 * 64 + lane];
                const float v2 = (float)xin[s2 * 64 + lane], v3 = (float)xin[s3 * 64 + lane];
                const float v4 = (float)xin[s4 * 64 + lane], v5 = (float)xin[s5 * 64 + lane];
                const float v6 = (float)xin[s6 * 64 + lane], v7 = (float)xin[s7 * 64 + lane];
                acc += ((v0 + v1) + (v2 + v3)) + ((v4 + v5) + (v6 + v7));
            }
            if (j + 4 <= cnt) {
                const int s0 = __shfl(s, j + 0), s1 = __shfl(s, j + 1);
                const int s2 = __shfl(s, j + 2), s3 = __shfl(s, j + 3);
                const float v0 = (float)xin[s0 * 64 + lane], v1 = (float)xin[s1 * 64 + lane];
                const float v2 = (float)xin[s2 * 64 + lane], v3 = (float)xin[s3 * 64 + lane];
                acc += (v0 + v1) + (v2 + v3);
                j += 4;
            }
            for (; j < cnt; ++j) {
                const int sj = __shfl(s, j);
                acc += (float)xin[sj * 64 + lane];
            }
        }
        hs[wv][m][lane] = (bf16_t)acc;              // 128B row, 2-way bank (free)
    }

    // ---- A fragments from aggregated tile (per-wave in-order LDS) ----
    bf16x8 af[2];
#pragma unroll
    for (int ks = 0; ks < 2; ++ks)
        af[ks] = *(const bf16x8*)(&hs[wv][l15][ks * 32 + quad * 8]);

    // GEMM1 -> relu -> hs (safe: af already in registers)
#pragma unroll
    for (int ct = 0; ct < 4; ++ct) {
        const bf16x8 b0 = *(const bf16x8*)&wfrag[0][ct * 2 + 0][lane][0];
        const bf16x8 b1 = *(const bf16x8*)&wfrag[0][ct * 2 + 1][lane][0];
        f32x4 acc = {0.f, 0.f, 0.f, 0.f};
        acc = __builtin_amdgcn_mfma_f32_16x16x32_bf16(af[0], b0, acc, 0, 0, 0);
        acc = __builtin_amdgcn_mfma_f32_16x16x32_bf16(af[1], b1, acc, 0, 0, 0);
        const float bv = biasA[ct * 16 + l15];
#pragma unroll
        for (int r = 0; r < 4; ++r) {
            float h = acc[r] + bv;
            h = h > 0.f ? h : 0.f;
            hs[wv][quad * 4 + r][ct * 16 + l15] = (bf16_t)h;
        }
    }

    bf16x8 a2[2];
#pragma unroll
    for (int ks = 0; ks < 2; ++ks)
        a2[ks] = *(const bf16x8*)(&hs[wv][l15][ks * 32 + quad * 8]);

    // GEMM2 -> relu -> hs
#pragma unroll
    for (int ct = 0; ct < 4; ++ct) {
        const bf16x8 b0 = *(const bf16x8*)&wfrag[1][ct * 2 + 0][lane][0];
        const bf16x8 b1 = *(const bf16x8*)&wfrag[1][ct * 2 + 1][lane][0];
        f32x4 acc = {0.f, 0.f, 0.f, 0.f};
        acc = __builtin_amdgcn_mfma_f32_16x16x32_bf16(a2[0], b0, acc, 0, 0, 0);
        acc = __builtin_amdgcn_mfma_f32_16x16x32_bf16(a2[1], b1, acc, 0, 0, 0);
        const float bv = biasB[ct * 16 + l15];
#pragma unroll
        for (int r = 0; r < 4; ++r) {
            float h = acc[r] + bv;
            h = h > 0.f ? h : 0.f;
            hs[wv][quad * 4 + r][ct * 16 + l15] = (bf16_t)h;
        }
    }

    if (POOL) {
        // segmented mean-pool numerator: one atomic per graph run per wave
        int cur = -1;
        float acc = 0.f;
        for (int r = 0; r < 16; ++r) {
            const int row = rb + r;
            if (row >= N_NODES) break;
            const int g = batch[row];               // wave-uniform
            const float v = (float)hs[wv][r][lane];
            if (g != cur) {
                if (cur >= 0) unsafeAtomicAdd(gsum + cur * 64 + lane, acc);
                acc = 0.f;
                cur = g;
            }
            acc += v;
        }
        if (cur >= 0) unsafeAtomicAdd(gsum + cur * 64 + lane, acc);
    } else {
        // coalesced store: 128B contiguous per instruction
        const int colg = (lane & 7) * 8;
#pragma unroll
        for (int sx = 0; sx < 2; ++sx) {
            const int r16 = (lane >> 3) + 8 * sx;
            const int grow = rb + r16;
            const bf16x8 v = *(const bf16x8*)&hs[wv][r16][colg];
            if (grow < N_NODES)
                *(bf16x8*)(xout + grow * 64 + colg) = v;
        }
    }
}

// out[g][c] = (gsum[g]/max(cnt,1)) . wc[:,c] + bc[c]; cnt via binary search
__global__ void cls_kernel(const float* __restrict__ gsum,
                           const int* __restrict__ batch,
                           const float* __restrict__ wc, const float* __restrict__ bc,
                           float* __restrict__ out) {
    const int g = blockIdx.x;
    const int c = threadIdx.x;
    if (c >= N_CLS) return;
    int lo = 0, hi = N_NODES;
    while (lo < hi) { const int m = (lo + hi) >> 1; if (batch[m] < g) lo = m + 1; else hi = m; }
    const int lb = lo;
    lo = 0; hi = N_NODES;
    while (lo < hi) { const int m = (lo + hi) >> 1; if (batch[m] <= g) lo = m + 1; else hi = m; }
    const int cnt = lo - lb;
    const float inv = 1.f / (float)(cnt > 1 ? cnt : 1);
    float acc = bc[c];
    for (int k = 0; k < 64; ++k)
        acc += gsum[g * 64 + k] * inv * wc[k * N_CLS + c];
    out[g * N_CLS + c] = acc;
}

// ---------------------------------------------------------------------------
extern "C" void kernel_launch(void* const* d_in, const int* in_sizes, int n_in,
                              void* d_out, int out_size, void* d_ws, size_t ws_size,
                              hipStream_t stream) {
    const float* x   = (const float*)d_in[0];
    const float* w1a = (const float*)d_in[1];
    const float* b1a = (const float*)d_in[2];
    const float* w1b = (const float*)d_in[3];
    const float* b1b = (const float*)d_in[4];
    const float* w2a = (const float*)d_in[5];
    const float* b2a = (const float*)d_in[6];
    const float* w2b = (const float*)d_in[7];
    const float* b2b = (const float*)d_in[8];
    const float* w3a = (const float*)d_in[9];
    const float* b3a = (const float*)d_in[10];
    const float* w3b = (const float*)d_in[11];
    const float* b3b = (const float*)d_in[12];
    const float* wc  = (const float*)d_in[13];
    const float* bc  = (const float*)d_in[14];
    const int*   ei    = (const int*)d_in[15];
    const int*   batch = (const int*)d_in[16];
    float* out = (float*)d_out;

    // workspace layout (~50.1 MB, 16B-aligned)
    char*   ws     = (char*)d_ws;
    int*    bcnt   = (int*)ws;                      // 391 ints (pad 1568)
    int*    cbase  = (int*)(ws + 1568);             // 391 ints (pad 1568)
    int*    offset = (int*)(ws + 3136);             // N+1 ints (pad 400016)
    int*    csr    = (int*)(ws + 403152);           // E ints = 4,800,000
    int*    bpair  = (int*)(ws + 5203152);          // 391*4096*4 = 6,406,144
    bf16_t* xbf    = (bf16_t*)(ws + 11609296);      // 12,800,000
    bf16_t* h      = (bf16_t*)(ws + 24409296);      // 12,800,000
    bf16_t* xA     = (bf16_t*)(ws + 37209296);      // 12,800,000
    float*  gsum   = (float*)(ws + 50009296);       // 32,768

    const int e4grid = (N_EDGES / 4 + 255) / 256;   // 1172
    const int lgrid  = (N_NODES + 63) / 64;         // 1563

    // x -> bf16
    tobf_kernel<<<(N_NODES * 64) / (256 * 8), 256, 0, stream>>>(x, xbf);

    // CSR build (once, reused 3x)
    hipMemsetAsync(bcnt, 0, 1568, stream);
    hipMemsetAsync(gsum, 0, 32768, stream);
    binA_kernel<<<e4grid, 256, 0, stream>>>(ei, bcnt, bpair);
    bscan_kernel<<<1, 512, 0, stream>>>(bcnt, cbase, offset);
    sortfill_kernel<<<NBUCK, 256, 0, stream>>>(bpair, bcnt, cbase, offset, csr);

    // fused layers
    layer_kernel<0><<<lgrid, 256, 0, stream>>>(xbf, offset, csr, w1a, b1a, w1b, b1b,
                                               xA, nullptr, nullptr);
    layer_kernel<0><<<lgrid, 256, 0, stream>>>(xA, offset, csr, w2a, b2a, w2b, b2b,
                                               h, nullptr, nullptr);
    layer_kernel<1><<<lgrid, 256, 0, stream>>>(h, offset, csr, w3a, b3a, w3b, b3b,
                                               nullptr, batch, gsum);

    // classify
    cls_kernel<<<N_GRAPH, 64, 0, stream>>>(gsum, batch, wc, bc, out);
}

// Round 10
// 335.341 us; speedup vs baseline: 1.1520x; 1.1520x over previous
//
#include <hip/hip_runtime.h>
#include <hip/hip_bf16.h>

// GIN: 3x [CSR gather-sum + MLP(64->64->64) + relu] + mean-pool(128) + linear(64->10)
// Split structure (r8; fusion regressed: gather is stream/latency-bound and
// fusion halved resident gather waves). agg2: TWO independent gather pipelines
// per wave (nodes w and w+50000), 8+8 batched loads -> up to 16 outstanding.
// CSR: 391-bucket binning + per-bucket counting sort. MLP: grid-stride tiles.

#define N_NODES 100000
#define N_EDGES 1200000
#define N_GRAPH 128
#define N_CLS   10
#define NBUCK   391        // dst >> 8
#define BCAP    4096       // per-bucket capacity (mean 3070, +18 sigma)
#define BSH     12         // log2(BCAP)
#define HALFN   50000

typedef __bf16 bf16_t;
typedef __bf16 bf16x8 __attribute__((ext_vector_type(8)));
typedef float  f32x4  __attribute__((ext_vector_type(4)));

// ---------------- x -> bf16 ----------------
__global__ void tobf_kernel(const float* __restrict__ x, bf16_t* __restrict__ xb) {
    const int i = (blockIdx.x * 256 + threadIdx.x) * 8;
    const f32x4 a = *(const f32x4*)(x + i);
    const f32x4 b = *(const f32x4*)(x + i + 4);
    bf16x8 o;
#pragma unroll
    for (int j = 0; j < 4; ++j) { o[j] = (bf16_t)a[j]; o[4 + j] = (bf16_t)b[j]; }
    *(bf16x8*)(xb + i) = o;
}

// ---------------- CSR build ----------------
__global__ void binA_kernel(const int* __restrict__ ei,
                            int* __restrict__ bcnt,
                            int* __restrict__ bpair) {
    __shared__ int lcnt[NBUCK];
    __shared__ int lbase[NBUCK];
    const int t = threadIdx.x;
    for (int b = t; b < NBUCK; b += 256) lcnt[b] = 0;
    __syncthreads();
    const int e0 = (blockIdx.x * 256 + t) * 4;
    int4 s4, d4; int b[4], r[4];
    const bool valid = e0 < N_EDGES;               // N_EDGES % 4 == 0
    if (valid) {
        s4 = *(const int4*)(ei + e0);
        d4 = *(const int4*)(ei + N_EDGES + e0);
        b[0] = d4.x >> 8; b[1] = d4.y >> 8; b[2] = d4.z >> 8; b[3] = d4.w >> 8;
        r[0] = atomicAdd(&lcnt[b[0]], 1);
        r[1] = atomicAdd(&lcnt[b[1]], 1);
        r[2] = atomicAdd(&lcnt[b[2]], 1);
        r[3] = atomicAdd(&lcnt[b[3]], 1);
    }
    __syncthreads();
    for (int bb = t; bb < NBUCK; bb += 256) {
        const int c = lcnt[bb];
        lbase[bb] = c ? atomicAdd(&bcnt[bb], c) : 0;
    }
    __syncthreads();
    if (valid) {
        const int ss[4] = {s4.x, s4.y, s4.z, s4.w};
        const int dd[4] = {d4.x, d4.y, d4.z, d4.w};
#pragma unroll
        for (int j = 0; j < 4; ++j) {
            const int slot = lbase[b[j]] + r[j];
            if (slot < BCAP)
                bpair[(b[j] << BSH) + slot] = (ss[j] << 8) | (dd[j] & 255);
        }
    }
}

__global__ void bscan_kernel(const int* __restrict__ bcnt, int* __restrict__ cbase,
                             int* __restrict__ offset) {
    __shared__ int l[512];
    const int t = threadIdx.x;
    const int v = (t < NBUCK) ? bcnt[t] : 0;
    l[t] = v;
    __syncthreads();
    for (int d = 1; d < 512; d <<= 1) {
        int u = l[t];
        if (t >= d) u += l[t - d];
        __syncthreads();
        l[t] = u;
        __syncthreads();
    }
    if (t < NBUCK) cbase[t] = l[t] - v;
    if (t == NBUCK - 1) offset[N_NODES] = l[t];
}

__global__ void sortfill_kernel(const int* __restrict__ bpair,
                                const int* __restrict__ bcnt,
                                const int* __restrict__ cbase,
                                int* __restrict__ offset, int* __restrict__ csr) {
    __shared__ int hist[256];
    __shared__ int l[256];
    __shared__ int cursor[256];
    const int b = blockIdx.x;
    const int t = threadIdx.x;
    const int base = b << BSH;
    int cnt = bcnt[b];
    cnt = cnt < BCAP ? cnt : BCAP;

    hist[t] = 0;
    __syncthreads();
    for (int i = t; i < cnt; i += 256)
        atomicAdd(&hist[bpair[base + i] & 255], 1);
    __syncthreads();

    const int v = hist[t];
    l[t] = v;
    __syncthreads();
    for (int d = 1; d < 256; d <<= 1) {
        int u = l[t];
        if (t >= d) u += l[t - d];
        __syncthreads();
        l[t] = u;
        __syncthreads();
    }
    const int gpos = cbase[b] + l[t] - v;           // exclusive
    const int node = (b << 8) + t;
    if (node < N_NODES) offset[node] = gpos;
    cursor[t] = gpos;
    __syncthreads();

    for (int i = t; i < cnt; i += 256) {
        const int p = bpair[base + i];
        const int pos = atomicAdd(&cursor[p & 255], 1);
        csr[pos] = p >> 8;
    }
}

// ---------------------------------------------------------------------------
// Dual-stream gather: wave w aggregates nodes w and w+50000 with two
// independent 8-deep load pipelines (up to 16 outstanding per wave).
// ---------------------------------------------------------------------------
#define GATHER8(S, ACC)                                                        \
    {                                                                          \
        const int t0 = __shfl(S, j + 0), t1 = __shfl(S, j + 1);                \
        const int t2 = __shfl(S, j + 2), t3 = __shfl(S, j + 3);                \
        const int t4 = __shfl(S, j + 4), t5 = __shfl(S, j + 5);                \
        const int t6 = __shfl(S, j + 6), t7 = __shfl(S, j + 7);                \
        const float u0 = (float)x[t0 * 64 + f], u1 = (float)x[t1 * 64 + f];    \
        const float u2 = (float)x[t2 * 64 + f], u3 = (float)x[t3 * 64 + f];    \
        const float u4 = (float)x[t4 * 64 + f], u5 = (float)x[t5 * 64 + f];    \
        const float u6 = (float)x[t6 * 64 + f], u7 = (float)x[t7 * 64 + f];    \
        ACC += ((u0 + u1) + (u2 + u3)) + ((u4 + u5) + (u6 + u7));              \
    }
#define GATHER4(S, J, ACC)                                                     \
    {                                                                          \
        const int t0 = __shfl(S, J + 0), t1 = __shfl(S, J + 1);                \
        const int t2 = __shfl(S, J + 2), t3 = __shfl(S, J + 3);                \
        const float u0 = (float)x[t0 * 64 + f], u1 = (float)x[t1 * 64 + f];    \
        const float u2 = (float)x[t2 * 64 + f], u3 = (float)x[t3 * 64 + f];    \
        ACC += (u0 + u1) + (u2 + u3);                                          \
    }

__global__ void agg2_kernel(const bf16_t* __restrict__ x,
                            const int* __restrict__ offset,
                            const int* __restrict__ csr,
                            bf16_t* __restrict__ hout) {
    const int w = (blockIdx.x * 256 + threadIdx.x) >> 6;   // 0..49999 (grid exact)
    const int f = threadIdx.x & 63;
    const int nA = w;
    const int nB = w + HALFN;

    const int oA = offset[nA], eA = offset[nA + 1];
    const int oB = offset[nB], eB = offset[nB + 1];
    const int dA = eA - oA, dB = eB - oB;

    float accA = (float)x[nA * 64 + f];
    float accB = (float)x[nB * 64 + f];

    for (int base = 0; base < dA || base < dB; base += 64) {
        const int ra = dA - base, rb2 = dB - base;
        const int cntA = ra <= 0 ? 0 : (ra < 64 ? ra : 64);
        const int cntB = rb2 <= 0 ? 0 : (rb2 < 64 ? rb2 : 64);
        int sA = 0, sB = 0;
        if (f < cntA) sA = csr[oA + base + f];
        if (f < cntB) sB = csr[oB + base + f];

        int j = 0;
        // dual full-8 batches: 16 loads in flight
        for (; j + 8 <= cntA && j + 8 <= cntB; j += 8) {
            GATHER8(sA, accA)
            GATHER8(sB, accB)
        }
        int jA = j, jB = j;
        for (; jA + 8 <= cntA; jA += 8) { const int j = jA; GATHER8(sA, accA) }
        for (; jB + 8 <= cntB; jB += 8) { const int j = jB; GATHER8(sB, accB) }
        if (jA + 4 <= cntA && jB + 4 <= cntB) {
            GATHER4(sA, jA, accA)
            GATHER4(sB, jB, accB)
            jA += 4; jB += 4;
        }
        if (jA + 4 <= cntA) { GATHER4(sA, jA, accA) jA += 4; }
        if (jB + 4 <= cntB) { GATHER4(sB, jB, accB) jB += 4; }
        for (; jA < cntA; ++jA) { const int t = __shfl(sA, jA); accA += (float)x[t * 64 + f]; }
        for (; jB < cntB; ++jB) { const int t = __shfl(sB, jB); accB += (float)x[t * 64 + f]; }
    }
    hout[nA * 64 + f] = (bf16_t)accA;
    hout[nB * 64 + f] = (bf16_t)accB;
}

// ---------------------------------------------------------------------------
// xout = bf16( relu( relu(hin @ wa + ba) @ wb + bb ) )
// Grid-stride: 521 blocks x 3 tiles; fragment-layout LDS weights; aliased tile.
// ---------------------------------------------------------------------------
__global__ void mlp_kernel(const bf16_t* __restrict__ hin,
                           const float* __restrict__ wa, const float* __restrict__ ba,
                           const float* __restrict__ wb, const float* __restrict__ bb,
                           bf16_t* __restrict__ xout) {
    __shared__ __align__(16) bf16_t wfrag[2][8][64][8];  // [mat][ct*2+ks][lane][j]
    __shared__ __align__(16) bf16_t hs[4][16][72];       // per-wave, reused h1/h2
    __shared__ float biasA[64], biasB[64];

    const int tid  = threadIdx.x;
    const int wv   = tid >> 6;
    const int lane = tid & 63;
    const int l15  = lane & 15;
    const int quad = lane >> 4;

    {
        const int k  = tid >> 2;
        const int n0 = (tid & 3) << 4;
        const int ks = k >> 5, qd = (k >> 3) & 3, jj = k & 7;
        const int fi = ((n0 >> 4) << 1) + ks;
#pragma unroll
        for (int m = 0; m < 2; ++m) {
            const float* w = m ? wb : wa;
            const f32x4 v0 = *(const f32x4*)(w + k * 64 + n0);
            const f32x4 v1 = *(const f32x4*)(w + k * 64 + n0 + 4);
            const f32x4 v2 = *(const f32x4*)(w + k * 64 + n0 + 8);
            const f32x4 v3 = *(const f32x4*)(w + k * 64 + n0 + 12);
#pragma unroll
            for (int l = 0; l < 4; ++l) {
                wfrag[m][fi][qd * 16 + l][jj]      = (bf16_t)v0[l];
                wfrag[m][fi][qd * 16 + 4 + l][jj]  = (bf16_t)v1[l];
                wfrag[m][fi][qd * 16 + 8 + l][jj]  = (bf16_t)v2[l];
                wfrag[m][fi][qd * 16 + 12 + l][jj] = (bf16_t)v3[l];
            }
        }
        if (tid < 64) biasA[tid] = ba[tid];
        else if (tid < 128) biasB[tid - 64] = bb[tid - 64];
    }
    __syncthreads();

    const int ntiles = (N_NODES + 63) / 64;   // 1563
    for (int tile = blockIdx.x; tile < ntiles; tile += gridDim.x) {
        const int rb = tile * 64 + wv * 16;
        const int rowa = rb + l15;
        const int rowc = rowa < N_NODES ? rowa : N_NODES - 1;

        bf16x8 af[2];
#pragma unroll
        for (int ks = 0; ks < 2; ++ks)
            af[ks] = *(const bf16x8*)(hin + rowc * 64 + ks * 32 + quad * 8);

#pragma unroll
        for (int ct = 0; ct < 4; ++ct) {
            const bf16x8 b0 = *(const bf16x8*)&wfrag[0][ct * 2 + 0][lane][0];
            const bf16x8 b1 = *(const bf16x8*)&wfrag[0][ct * 2 + 1][lane][0];
            f32x4 acc = {0.f, 0.f, 0.f, 0.f};
            acc = __builtin_amdgcn_mfma_f32_16x16x32_bf16(af[0], b0, acc, 0, 0, 0);
            acc = __builtin_amdgcn_mfma_f32_16x16x32_bf16(af[1], b1, acc, 0, 0, 0);
            const float bv = biasA[ct * 16 + l15];
#pragma unroll
            for (int r = 0; r < 4; ++r) {
                float h = acc[r] + bv;
                h = h > 0.f ? h : 0.f;
                hs[wv][quad * 4 + r][ct * 16 + l15] = (bf16_t)h;
            }
        }

        bf16x8 a2[2];
#pragma unroll
        for (int ks = 0; ks < 2; ++ks)
            a2[ks] = *(const bf16x8*)(&hs[wv][l15][ks * 32 + quad * 8]);

#pragma unroll
        for (int ct = 0; ct < 4; ++ct) {
            const bf16x8 b0 = *(const bf16x8*)&wfrag[1][ct * 2 + 0][lane][0];
            const bf16x8 b1 = *(const bf16x8*)&wfrag[1][ct * 2 + 1][lane][0];
            f32x4 acc = {0.f, 0.f, 0.f, 0.f};
            acc = __builtin_amdgcn_mfma_f32_16x16x32_bf16(a2[0], b0, acc, 0, 0, 0);
            acc = __builtin_amdgcn_mfma_f32_16x16x32_bf16(a2[1], b1, acc, 0, 0, 0);
            const float bv = biasB[ct * 16 + l15];
#pragma unroll
            for (int r = 0; r < 4; ++r) {
                float h = acc[r] + bv;
                h = h > 0.f ? h : 0.f;
                hs[wv][quad * 4 + r][ct * 16 + l15] = (bf16_t)h;
            }
        }

        const int colg = (lane & 7) * 8;
#pragma unroll
        for (int sx = 0; sx < 2; ++sx) {
            const int r16 = (lane >> 3) + 8 * sx;
            const int grow = rb + r16;
            const bf16x8 v = *(const bf16x8*)&hs[wv][r16][colg];
            if (grow < N_NODES)
                *(bf16x8*)(xout + grow * 64 + colg) = v;
        }
    }
}

// ---------------------------------------------------------------------------
// Mean-pool numerator: one wave per 16 nodes, flush on transition.
// ---------------------------------------------------------------------------
__global__ void pool_kernel(const bf16_t* __restrict__ x,
                            const int* __restrict__ batch,
                            float* __restrict__ gsum) {
    const int f  = threadIdx.x & 63;
    const int wv = threadIdx.x >> 6;
    const int n0 = (blockIdx.x * 4 + wv) * 16;
    if (n0 >= N_NODES) return;
    const int n1 = (n0 + 16 < N_NODES) ? (n0 + 16) : N_NODES;
    int cur = batch[n0];
    float acc = 0.f;
    for (int n = n0; n < n1; ++n) {
        const int g = batch[n];
        const float v = (float)x[n * 64 + f];
        if (g != cur) {
            unsafeAtomicAdd(gsum + cur * 64 + f, acc);
            acc = 0.f;
            cur = g;
        }
        acc += v;
    }
    unsafeAtomicAdd(gsum + cur * 64 + f, acc);
}

__global__ void cls_kernel(const float* __restrict__ gsum,
                           const int* __restrict__ batch,
                           const float* __restrict__ wc, const float* __restrict__ bc,
                           float* __restrict__ out) {
    const int g = blockIdx.x;
    const int c = threadIdx.x;
    if (c >= N_CLS) return;
    int lo = 0, hi = N_NODES;
    while (lo < hi) { const int m = (lo + hi) >> 1; if (batch[m] < g) lo = m + 1; else hi = m; }
    const int lb = lo;
    lo = 0; hi = N_NODES;
    while (lo < hi) { const int m = (lo + hi) >> 1; if (batch[m] <= g) lo = m + 1; else hi = m; }
    const int cnt = lo - lb;
    const float inv = 1.f / (float)(cnt > 1 ? cnt : 1);
    float acc = bc[c];
    for (int k = 0; k < 64; ++k)
        acc += gsum[g * 64 + k] * inv * wc[k * N_CLS + c];
    out[g * N_CLS + c] = acc;
}

// ---------------------------------------------------------------------------
extern "C" void kernel_launch(void* const* d_in, const int* in_sizes, int n_in,
                              void* d_out, int out_size, void* d_ws, size_t ws_size,
                              hipStream_t stream) {
    const float* x   = (const float*)d_in[0];
    const float* w1a = (const float*)d_in[1];
    const float* b1a = (const float*)d_in[2];
    const float* w1b = (const float*)d_in[3];
    const float* b1b = (const float*)d_in[4];
    const float* w2a = (const float*)d_in[5];
    const float* b2a = (const float*)d_in[6];
    const float* w2b = (const float*)d_in[7];
    const float* b2b = (const float*)d_in[8];
    const float* w3a = (const float*)d_in[9];
    const float* b3a = (const float*)d_in[10];
    const float* w3b = (const float*)d_in[11];
    const float* b3b = (const float*)d_in[12];
    const float* wc  = (const float*)d_in[13];
    const float* bc  = (const float*)d_in[14];
    const int*   ei    = (const int*)d_in[15];
    const int*   batch = (const int*)d_in[16];
    float* out = (float*)d_out;

    // workspace layout (~50.1 MB, 16B-aligned)
    char*   ws     = (char*)d_ws;
    int*    bcnt   = (int*)ws;                      // 391 ints (pad 1568)
    int*    cbase  = (int*)(ws + 1568);             // 391 ints (pad 1568)
    int*    offset = (int*)(ws + 3136);             // N+1 ints (pad 400016)
    int*    csr    = (int*)(ws + 403152);           // E ints = 4,800,000
    int*    bpair  = (int*)(ws + 5203152);          // 391*4096*4 = 6,406,144
    bf16_t* xbf    = (bf16_t*)(ws + 11609296);      // 12,800,000
    bf16_t* h      = (bf16_t*)(ws + 24409296);      // 12,800,000
    bf16_t* xA     = (bf16_t*)(ws + 37209296);      // 12,800,000
    float*  gsum   = (float*)(ws + 50009296);       // 32,768

    const int e4grid  = (N_EDGES / 4 + 255) / 256;  // 1172
    const int a2grid  = HALFN / 4;                  // 12500 (2 nodes/wave, exact)
    const int mlpgrid = 521;                        // 3 tiles/block
    const int pgrid   = (N_NODES + 63) / 64;        // 1563

    // x -> bf16
    tobf_kernel<<<(N_NODES * 64) / (256 * 8), 256, 0, stream>>>(x, xbf);

    // CSR build (once, reused 3x)
    hipMemsetAsync(bcnt, 0, 1568, stream);
    hipMemsetAsync(gsum, 0, 32768, stream);
    binA_kernel<<<e4grid, 256, 0, stream>>>(ei, bcnt, bpair);
    bscan_kernel<<<1, 512, 0, stream>>>(bcnt, cbase, offset);
    sortfill_kernel<<<NBUCK, 256, 0, stream>>>(bpair, bcnt, cbase, offset, csr);

    // layer 1
    agg2_kernel<<<a2grid, 256, 0, stream>>>(xbf, offset, csr, h);
    mlp_kernel<<<mlpgrid, 256, 0, stream>>>(h, w1a, b1a, w1b, b1b, xA);
    // layer 2
    agg2_kernel<<<a2grid, 256, 0, stream>>>(xA, offset, csr, h);
    mlp_kernel<<<mlpgrid, 256, 0, stream>>>(h, w2a, b2a, w2b, b2b, xA);
    // layer 3
    agg2_kernel<<<a2grid, 256, 0, stream>>>(xA, offset, csr, h);
    mlp_kernel<<<mlpgrid, 256, 0, stream>>>(h, w3a, b3a, w3b, b3b, xA);

    // pool + classify
    pool_kernel<<<pgrid, 256, 0, stream>>>(xA, batch, gsum);
    cls_kernel<<<N_GRAPH, 64, 0, stream>>>(gsum, batch, wc, bc, out);
}

// Round 11
// 329.847 us; speedup vs baseline: 1.1712x; 1.0167x over previous
//
#include <hip/hip_runtime.h>
#include <hip/hip_bf16.h>

// GIN: 3x [CSR gather-sum + MLP(64->64->64) + relu] + mean-pool(128) + linear(64->10)
// Split structure (fusion of agg+mlp regressed: gather is fabric-bound and
// needs max resident gather waves). agg2: dual gather pipelines per wave.
// MLP: grid-stride tiles; layer 3 fuses the mean-pool epilogue (POOL=1).
// CSR: 391-bucket binning + per-bucket counting sort, built once per launch.

#define N_NODES 100000
#define N_EDGES 1200000
#define N_GRAPH 128
#define N_CLS   10
#define NBUCK   391        // dst >> 8
#define BCAP    4096       // per-bucket capacity (mean 3070, +18 sigma)
#define BSH     12         // log2(BCAP)
#define HALFN   50000

typedef __bf16 bf16_t;
typedef __bf16 bf16x8 __attribute__((ext_vector_type(8)));
typedef float  f32x4  __attribute__((ext_vector_type(4)));

// ---------------- x -> bf16 ----------------
__global__ void tobf_kernel(const float* __restrict__ x, bf16_t* __restrict__ xb) {
    const int i = (blockIdx.x * 256 + threadIdx.x) * 8;
    const f32x4 a = *(const f32x4*)(x + i);
    const f32x4 b = *(const f32x4*)(x + i + 4);
    bf16x8 o;
#pragma unroll
    for (int j = 0; j < 4; ++j) { o[j] = (bf16_t)a[j]; o[4 + j] = (bf16_t)b[j]; }
    *(bf16x8*)(xb + i) = o;
}

// ---------------- CSR build ----------------
__global__ void binA_kernel(const int* __restrict__ ei,
                            int* __restrict__ bcnt,
                            int* __restrict__ bpair) {
    __shared__ int lcnt[NBUCK];
    __shared__ int lbase[NBUCK];
    const int t = threadIdx.x;
    for (int b = t; b < NBUCK; b += 256) lcnt[b] = 0;
    __syncthreads();
    const int e0 = (blockIdx.x * 256 + t) * 4;
    int4 s4, d4; int b[4], r[4];
    const bool valid = e0 < N_EDGES;               // N_EDGES % 4 == 0
    if (valid) {
        s4 = *(const int4*)(ei + e0);
        d4 = *(const int4*)(ei + N_EDGES + e0);
        b[0] = d4.x >> 8; b[1] = d4.y >> 8; b[2] = d4.z >> 8; b[3] = d4.w >> 8;
        r[0] = atomicAdd(&lcnt[b[0]], 1);
        r[1] = atomicAdd(&lcnt[b[1]], 1);
        r[2] = atomicAdd(&lcnt[b[2]], 1);
        r[3] = atomicAdd(&lcnt[b[3]], 1);
    }
    __syncthreads();
    for (int bb = t; bb < NBUCK; bb += 256) {
        const int c = lcnt[bb];
        lbase[bb] = c ? atomicAdd(&bcnt[bb], c) : 0;
    }
    __syncthreads();
    if (valid) {
        const int ss[4] = {s4.x, s4.y, s4.z, s4.w};
        const int dd[4] = {d4.x, d4.y, d4.z, d4.w};
#pragma unroll
        for (int j = 0; j < 4; ++j) {
            const int slot = lbase[b[j]] + r[j];
            if (slot < BCAP)
                bpair[(b[j] << BSH) + slot] = (ss[j] << 8) | (dd[j] & 255);
        }
    }
}

__global__ void bscan_kernel(const int* __restrict__ bcnt, int* __restrict__ cbase,
                             int* __restrict__ offset) {
    __shared__ int l[512];
    const int t = threadIdx.x;
    const int v = (t < NBUCK) ? bcnt[t] : 0;
    l[t] = v;
    __syncthreads();
    for (int d = 1; d < 512; d <<= 1) {
        int u = l[t];
        if (t >= d) u += l[t - d];
        __syncthreads();
        l[t] = u;
        __syncthreads();
    }
    if (t < NBUCK) cbase[t] = l[t] - v;
    if (t == NBUCK - 1) offset[N_NODES] = l[t];
}

__global__ void sortfill_kernel(const int* __restrict__ bpair,
                                const int* __restrict__ bcnt,
                                const int* __restrict__ cbase,
                                int* __restrict__ offset, int* __restrict__ csr) {
    __shared__ int hist[256];
    __shared__ int l[256];
    __shared__ int cursor[256];
    const int b = blockIdx.x;
    const int t = threadIdx.x;
    const int base = b << BSH;
    int cnt = bcnt[b];
    cnt = cnt < BCAP ? cnt : BCAP;

    hist[t] = 0;
    __syncthreads();
    for (int i = t; i < cnt; i += 256)
        atomicAdd(&hist[bpair[base + i] & 255], 1);
    __syncthreads();

    const int v = hist[t];
    l[t] = v;
    __syncthreads();
    for (int d = 1; d < 256; d <<= 1) {
        int u = l[t];
        if (t >= d) u += l[t - d];
        __syncthreads();
        l[t] = u;
        __syncthreads();
    }
    const int gpos = cbase[b] + l[t] - v;           // exclusive
    const int node = (b << 8) + t;
    if (node < N_NODES) offset[node] = gpos;
    cursor[t] = gpos;
    __syncthreads();

    for (int i = t; i < cnt; i += 256) {
        const int p = bpair[base + i];
        const int pos = atomicAdd(&cursor[p & 255], 1);
        csr[pos] = p >> 8;
    }
}

// ---------------------------------------------------------------------------
// Dual-stream gather: wave w aggregates nodes w and w+50000 with two
// independent 8-deep load pipelines.
// ---------------------------------------------------------------------------
#define GATHER8(S, ACC)                                                        \
    {                                                                          \
        const int t0 = __shfl(S, j + 0), t1 = __shfl(S, j + 1);                \
        const int t2 = __shfl(S, j + 2), t3 = __shfl(S, j + 3);                \
        const int t4 = __shfl(S, j + 4), t5 = __shfl(S, j + 5);                \
        const int t6 = __shfl(S, j + 6), t7 = __shfl(S, j + 7);                \
        const float u0 = (float)x[t0 * 64 + f], u1 = (float)x[t1 * 64 + f];    \
        const float u2 = (float)x[t2 * 64 + f], u3 = (float)x[t3 * 64 + f];    \
        const float u4 = (float)x[t4 * 64 + f], u5 = (float)x[t5 * 64 + f];    \
        const float u6 = (float)x[t6 * 64 + f], u7 = (float)x[t7 * 64 + f];    \
        ACC += ((u0 + u1) + (u2 + u3)) + ((u4 + u5) + (u6 + u7));              \
    }
#define GATHER4(S, J, ACC)                                                     \
    {                                                                          \
        const int t0 = __shfl(S, J + 0), t1 = __shfl(S, J + 1);                \
        const int t2 = __shfl(S, J + 2), t3 = __shfl(S, J + 3);                \
        const float u0 = (float)x[t0 * 64 + f], u1 = (float)x[t1 * 64 + f];    \
        const float u2 = (float)x[t2 * 64 + f], u3 = (float)x[t3 * 64 + f];    \
        ACC += (u0 + u1) + (u2 + u3);                                          \
    }

__global__ void agg2_kernel(const bf16_t* __restrict__ x,
                            const int* __restrict__ offset,
                            const int* __restrict__ csr,
                            bf16_t* __restrict__ hout) {
    const int w = (blockIdx.x * 256 + threadIdx.x) >> 6;   // 0..49999 (grid exact)
    const int f = threadIdx.x & 63;
    const int nA = w;
    const int nB = w + HALFN;

    const int oA = offset[nA], eA = offset[nA + 1];
    const int oB = offset[nB], eB = offset[nB + 1];
    const int dA = eA - oA, dB = eB - oB;

    float accA = (float)x[nA * 64 + f];
    float accB = (float)x[nB * 64 + f];

    for (int base = 0; base < dA || base < dB; base += 64) {
        const int ra = dA - base, rb2 = dB - base;
        const int cntA = ra <= 0 ? 0 : (ra < 64 ? ra : 64);
        const int cntB = rb2 <= 0 ? 0 : (rb2 < 64 ? rb2 : 64);
        int sA = 0, sB = 0;
        if (f < cntA) sA = csr[oA + base + f];
        if (f < cntB) sB = csr[oB + base + f];

        int j = 0;
        for (; j + 8 <= cntA && j + 8 <= cntB; j += 8) {
            GATHER8(sA, accA)
            GATHER8(sB, accB)
        }
        int jA = j, jB = j;
        for (; jA + 8 <= cntA; jA += 8) { const int j = jA; GATHER8(sA, accA) }
        for (; jB + 8 <= cntB; jB += 8) { const int j = jB; GATHER8(sB, accB) }
        if (jA + 4 <= cntA && jB + 4 <= cntB) {
            GATHER4(sA, jA, accA)
            GATHER4(sB, jB, accB)
            jA += 4; jB += 4;
        }
        if (jA + 4 <= cntA) { GATHER4(sA, jA, accA) jA += 4; }
        if (jB + 4 <= cntB) { GATHER4(sB, jB, accB) jB += 4; }
        for (; jA < cntA; ++jA) { const int t = __shfl(sA, jA); accA += (float)x[t * 64 + f]; }
        for (; jB < cntB; ++jB) { const int t = __shfl(sB, jB); accB += (float)x[t * 64 + f]; }
    }
    hout[nA * 64 + f] = (bf16_t)accA;
    hout[nB * 64 + f] = (bf16_t)accB;
}

// ---------------------------------------------------------------------------
// MLP: xout = bf16( relu( relu(hin @ wa + ba) @ wb + bb ) )
// Grid-stride (782 blocks x ~2 tiles); fragment-layout LDS weights; aliased
// per-wave tile. POOL=1 (layer 3): segmented mean-pool numerator into gsum
// atomics instead of storing rows.
// ---------------------------------------------------------------------------
template <int POOL>
__global__ void mlp_kernel(const bf16_t* __restrict__ hin,
                           const float* __restrict__ wa, const float* __restrict__ ba,
                           const float* __restrict__ wb, const float* __restrict__ bb,
                           bf16_t* __restrict__ xout,
                           const int* __restrict__ batch,
                           float* __restrict__ gsum) {
    __shared__ __align__(16) bf16_t wfrag[2][8][64][8];  // [mat][ct*2+ks][lane][j]
    __shared__ __align__(16) bf16_t hs[4][16][72];       // per-wave, reused h1/h2
    __shared__ float biasA[64], biasB[64];

    const int tid  = threadIdx.x;
    const int wv   = tid >> 6;
    const int lane = tid & 63;
    const int l15  = lane & 15;
    const int quad = lane >> 4;

    {
        const int k  = tid >> 2;
        const int n0 = (tid & 3) << 4;
        const int ks = k >> 5, qd = (k >> 3) & 3, jj = k & 7;
        const int fi = ((n0 >> 4) << 1) + ks;
#pragma unroll
        for (int m = 0; m < 2; ++m) {
            const float* w = m ? wb : wa;
            const f32x4 v0 = *(const f32x4*)(w + k * 64 + n0);
            const f32x4 v1 = *(const f32x4*)(w + k * 64 + n0 + 4);
            const f32x4 v2 = *(const f32x4*)(w + k * 64 + n0 + 8);
            const f32x4 v3 = *(const f32x4*)(w + k * 64 + n0 + 12);
#pragma unroll
            for (int l = 0; l < 4; ++l) {
                wfrag[m][fi][qd * 16 + l][jj]      = (bf16_t)v0[l];
                wfrag[m][fi][qd * 16 + 4 + l][jj]  = (bf16_t)v1[l];
                wfrag[m][fi][qd * 16 + 8 + l][jj]  = (bf16_t)v2[l];
                wfrag[m][fi][qd * 16 + 12 + l][jj] = (bf16_t)v3[l];
            }
        }
        if (tid < 64) biasA[tid] = ba[tid];
        else if (tid < 128) biasB[tid - 64] = bb[tid - 64];
    }
    __syncthreads();

    const int ntiles = (N_NODES + 63) / 64;   // 1563
    for (int tile = blockIdx.x; tile < ntiles; tile += gridDim.x) {
        const int rb = tile * 64 + wv * 16;
        const int rowa = rb + l15;
        const int rowc = rowa < N_NODES ? rowa : N_NODES - 1;

        bf16x8 af[2];
#pragma unroll
        for (int ks = 0; ks < 2; ++ks)
            af[ks] = *(const bf16x8*)(hin + rowc * 64 + ks * 32 + quad * 8);

        // GEMM1 -> relu -> hs
#pragma unroll
        for (int ct = 0; ct < 4; ++ct) {
            const bf16x8 b0 = *(const bf16x8*)&wfrag[0][ct * 2 + 0][lane][0];
            const bf16x8 b1 = *(const bf16x8*)&wfrag[0][ct * 2 + 1][lane][0];
            f32x4 acc = {0.f, 0.f, 0.f, 0.f};
            acc = __builtin_amdgcn_mfma_f32_16x16x32_bf16(af[0], b0, acc, 0, 0, 0);
            acc = __builtin_amdgcn_mfma_f32_16x16x32_bf16(af[1], b1, acc, 0, 0, 0);
            const float bv = biasA[ct * 16 + l15];
#pragma unroll
            for (int r = 0; r < 4; ++r) {
                float h = acc[r] + bv;
                h = h > 0.f ? h : 0.f;
                hs[wv][quad * 4 + r][ct * 16 + l15] = (bf16_t)h;
            }
        }

        bf16x8 a2[2];
#pragma unroll
        for (int ks = 0; ks < 2; ++ks)
            a2[ks] = *(const bf16x8*)(&hs[wv][l15][ks * 32 + quad * 8]);

        // GEMM2 -> relu -> hs
#pragma unroll
        for (int ct = 0; ct < 4; ++ct) {
            const bf16x8 b0 = *(const bf16x8*)&wfrag[1][ct * 2 + 0][lane][0];
            const bf16x8 b1 = *(const bf16x8*)&wfrag[1][ct * 2 + 1][lane][0];
            f32x4 acc = {0.f, 0.f, 0.f, 0.f};
            acc = __builtin_amdgcn_mfma_f32_16x16x32_bf16(a2[0], b0, acc, 0, 0, 0);
            acc = __builtin_amdgcn_mfma_f32_16x16x32_bf16(a2[1], b1, acc, 0, 0, 0);
            const float bv = biasB[ct * 16 + l15];
#pragma unroll
            for (int r = 0; r < 4; ++r) {
                float h = acc[r] + bv;
                h = h > 0.f ? h : 0.f;
                hs[wv][quad * 4 + r][ct * 16 + l15] = (bf16_t)h;
            }
        }

        if (POOL) {
            // segmented mean-pool numerator: ~1 atomic per graph run per wave
            int cur = -1;
            float acc = 0.f;
            for (int r = 0; r < 16; ++r) {
                const int row = rb + r;
                if (row >= N_NODES) break;
                const int g = batch[row];           // wave-uniform
                const float v = (float)hs[wv][r][lane];
                if (g != cur) {
                    if (cur >= 0) unsafeAtomicAdd(gsum + cur * 64 + lane, acc);
                    acc = 0.f;
                    cur = g;
                }
                acc += v;
            }
            if (cur >= 0) unsafeAtomicAdd(gsum + cur * 64 + lane, acc);
        } else {
            const int colg = (lane & 7) * 8;
#pragma unroll
            for (int sx = 0; sx < 2; ++sx) {
                const int r16 = (lane >> 3) + 8 * sx;
                const int grow = rb + r16;
                const bf16x8 v = *(const bf16x8*)&hs[wv][r16][colg];
                if (grow < N_NODES)
                    *(bf16x8*)(xout + grow * 64 + colg) = v;
            }
        }
    }
}

// out[g][c] = (gsum[g]/max(cnt,1)) . wc[:,c] + bc[c]; cnt via binary search
__global__ void cls_kernel(const float* __restrict__ gsum,
                           const int* __restrict__ batch,
                           const float* __restrict__ wc, const float* __restrict__ bc,
                           float* __restrict__ out) {
    const int g = blockIdx.x;
    const int c = threadIdx.x;
    if (c >= N_CLS) return;
    int lo = 0, hi = N_NODES;
    while (lo < hi) { const int m = (lo + hi) >> 1; if (batch[m] < g) lo = m + 1; else hi = m; }
    const int lb = lo;
    lo = 0; hi = N_NODES;
    while (lo < hi) { const int m = (lo + hi) >> 1; if (batch[m] <= g) lo = m + 1; else hi = m; }
    const int cnt = lo - lb;
    const float inv = 1.f / (float)(cnt > 1 ? cnt : 1);
    float acc = bc[c];
    for (int k = 0; k < 64; ++k)
        acc += gsum[g * 64 + k] * inv * wc[k * N_CLS + c];
    out[g * N_CLS + c] = acc;
}

// ---------------------------------------------------------------------------
extern "C" void kernel_launch(void* const* d_in, const int* in_sizes, int n_in,
                              void* d_out, int out_size, void* d_ws, size_t ws_size,
                              hipStream_t stream) {
    const float* x   = (const float*)d_in[0];
    const float* w1a = (const float*)d_in[1];
    const float* b1a = (const float*)d_in[2];
    const float* w1b = (const float*)d_in[3];
    const float* b1b = (const float*)d_in[4];
    const float* w2a = (const float*)d_in[5];
    const float* b2a = (const float*)d_in[6];
    const float* w2b = (const float*)d_in[7];
    const float* b2b = (const float*)d_in[8];
    const float* w3a = (const float*)d_in[9];
    const float* b3a = (const float*)d_in[10];
    const float* w3b = (const float*)d_in[11];
    const float* b3b = (const float*)d_in[12];
    const float* wc  = (const float*)d_in[13];
    const float* bc  = (const float*)d_in[14];
    const int*   ei    = (const int*)d_in[15];
    const int*   batch = (const int*)d_in[16];
    float* out = (float*)d_out;

    // workspace layout (~50.1 MB, 16B-aligned)
    char*   ws     = (char*)d_ws;
    int*    bcnt   = (int*)ws;                      // 391 ints (pad 1568)
    int*    cbase  = (int*)(ws + 1568);             // 391 ints (pad 1568)
    int*    offset = (int*)(ws + 3136);             // N+1 ints (pad 400016)
    int*    csr    = (int*)(ws + 403152);           // E ints = 4,800,000
    int*    bpair  = (int*)(ws + 5203152);          // 391*4096*4 = 6,406,144
    bf16_t* xbf    = (bf16_t*)(ws + 11609296);      // 12,800,000
    bf16_t* h      = (bf16_t*)(ws + 24409296);      // 12,800,000
    bf16_t* xA     = (bf16_t*)(ws + 37209296);      // 12,800,000
    float*  gsum   = (float*)(ws + 50009296);       // 32,768

    const int e4grid  = (N_EDGES / 4 + 255) / 256;  // 1172
    const int a2grid  = HALFN / 4;                  // 12500 (2 nodes/wave, exact)
    const int mlpgrid = 782;                        // ~2 tiles/block

    // x -> bf16
    tobf_kernel<<<(N_NODES * 64) / (256 * 8), 256, 0, stream>>>(x, xbf);

    // CSR build (once, reused 3x)
    hipMemsetAsync(bcnt, 0, 1568, stream);
    hipMemsetAsync(gsum, 0, 32768, stream);
    binA_kernel<<<e4grid, 256, 0, stream>>>(ei, bcnt, bpair);
    bscan_kernel<<<1, 512, 0, stream>>>(bcnt, cbase, offset);
    sortfill_kernel<<<NBUCK, 256, 0, stream>>>(bpair, bcnt, cbase, offset, csr);

    // layer 1
    agg2_kernel<<<a2grid, 256, 0, stream>>>(xbf, offset, csr, h);
    mlp_kernel<0><<<mlpgrid, 256, 0, stream>>>(h, w1a, b1a, w1b, b1b, xA, nullptr, nullptr);
    // layer 2
    agg2_kernel<<<a2grid, 256, 0, stream>>>(xA, offset, csr, h);
    mlp_kernel<0><<<mlpgrid, 256, 0, stream>>>(h, w2a, b2a, w2b, b2b, xA, nullptr, nullptr);
    // layer 3 (fused pooling epilogue)
    agg2_kernel<<<a2grid, 256, 0, stream>>>(xA, offset, csr, h);
    mlp_kernel<1><<<mlpgrid, 256, 0, stream>>>(h, w3a, b3a, w3b, b3b, nullptr, batch, gsum);

    // classify
    cls_kernel<<<N_GRAPH, 64, 0, stream>>>(gsum, batch, wc, bc, out);
}

// Round 12
// 323.244 us; speedup vs baseline: 1.1951x; 1.0204x over previous
//
#include <hip/hip_runtime.h>
#include <hip/hip_bf16.h>

// GIN: 3x [CSR gather-sum + MLP(64->64->64) + relu] + mean-pool(128) + linear(64->10)
// agg2: dual gather pipelines/wave, fabric-BW-bound (119MB @ ~3 TB/s, r10 A/B).
// MLP: 782 blocks x <=2 tiles, prefetched A-frags; layer 3 fuses pool epilogue.
// CSR: 391-bucket binning + per-bucket counting sort w/ inline prefix (no bscan).
// tobf zeroes bcnt+gsum (no memsets). 10 dispatches total.

#define N_NODES 100000
#define N_EDGES 1200000
#define N_GRAPH 128
#define N_CLS   10
#define NBUCK   391        // dst >> 8
#define BCAP    4096       // per-bucket capacity (mean 3070, +18 sigma)
#define BSH     12         // log2(BCAP)
#define HALFN   50000

typedef __bf16 bf16_t;
typedef __bf16 bf16x8 __attribute__((ext_vector_type(8)));
typedef float  f32x4  __attribute__((ext_vector_type(4)));

// ---------------- x -> bf16 (+ zero bcnt/gsum for later kernels) ----------------
__global__ void tobf_kernel(const float* __restrict__ x, bf16_t* __restrict__ xb,
                            int* __restrict__ bcnt, float* __restrict__ gsum) {
    if (blockIdx.x == 0) {
        for (int i = threadIdx.x; i < NBUCK; i += 256) bcnt[i] = 0;
    } else if (blockIdx.x == 1) {
        f32x4* g4 = (f32x4*)gsum;
        for (int i = threadIdx.x; i < N_GRAPH * 16; i += 256)   // 8192 f32
            g4[i] = (f32x4){0.f, 0.f, 0.f, 0.f};
    }
    const int i = (blockIdx.x * 256 + threadIdx.x) * 8;
    const f32x4 a = *(const f32x4*)(x + i);
    const f32x4 b = *(const f32x4*)(x + i + 4);
    bf16x8 o;
#pragma unroll
    for (int j = 0; j < 4; ++j) { o[j] = (bf16_t)a[j]; o[4 + j] = (bf16_t)b[j]; }
    *(bf16x8*)(xb + i) = o;
}

// ---------------- CSR build ----------------
__global__ void binA_kernel(const int* __restrict__ ei,
                            int* __restrict__ bcnt,
                            int* __restrict__ bpair) {
    __shared__ int lcnt[NBUCK];
    __shared__ int lbase[NBUCK];
    const int t = threadIdx.x;
    for (int b = t; b < NBUCK; b += 256) lcnt[b] = 0;
    __syncthreads();
    const int e0 = (blockIdx.x * 256 + t) * 4;
    int4 s4, d4; int b[4], r[4];
    const bool valid = e0 < N_EDGES;               // N_EDGES % 4 == 0
    if (valid) {
        s4 = *(const int4*)(ei + e0);
        d4 = *(const int4*)(ei + N_EDGES + e0);
        b[0] = d4.x >> 8; b[1] = d4.y >> 8; b[2] = d4.z >> 8; b[3] = d4.w >> 8;
        r[0] = atomicAdd(&lcnt[b[0]], 1);
        r[1] = atomicAdd(&lcnt[b[1]], 1);
        r[2] = atomicAdd(&lcnt[b[2]], 1);
        r[3] = atomicAdd(&lcnt[b[3]], 1);
    }
    __syncthreads();
    for (int bb = t; bb < NBUCK; bb += 256) {
        const int c = lcnt[bb];
        lbase[bb] = c ? atomicAdd(&bcnt[bb], c) : 0;
    }
    __syncthreads();
    if (valid) {
        const int ss[4] = {s4.x, s4.y, s4.z, s4.w};
        const int dd[4] = {d4.x, d4.y, d4.z, d4.w};
#pragma unroll
        for (int j = 0; j < 4; ++j) {
            const int slot = lbase[b[j]] + r[j];
            if (slot < BCAP)
                bpair[(b[j] << BSH) + slot] = (ss[j] << 8) | (dd[j] & 255);
        }
    }
}

// one WG per bucket: inline prefix over min(bcnt,BCAP) + LDS counting sort
__global__ void sortfill_kernel(const int* __restrict__ bpair,
                                const int* __restrict__ bcnt,
                                int* __restrict__ offset, int* __restrict__ csr) {
    __shared__ int red[256];
    __shared__ int hist[256];
    __shared__ int l[256];
    __shared__ int cursor[256];
    const int b = blockIdx.x;
    const int t = threadIdx.x;
    const int base = b << BSH;

    // prefix: cbase = sum_{i<b} min(bcnt[i],BCAP); cnt = min(bcnt[b],BCAP)
    int part = 0;
    for (int i = t; i < b; i += 256) {
        int c = bcnt[i];
        part += (c < BCAP ? c : BCAP);
    }
    red[t] = part;
    __syncthreads();
    for (int d = 128; d > 0; d >>= 1) {
        if (t < d) red[t] += red[t + d];
        __syncthreads();
    }
    const int cbase = red[0];
    int cnt = bcnt[b];
    cnt = cnt < BCAP ? cnt : BCAP;
    if (b == NBUCK - 1 && t == 0) offset[N_NODES] = cbase + cnt;
    __syncthreads();

    hist[t] = 0;
    __syncthreads();
    for (int i = t; i < cnt; i += 256)
        atomicAdd(&hist[bpair[base + i] & 255], 1);
    __syncthreads();

    const int v = hist[t];
    l[t] = v;
    __syncthreads();
    for (int d = 1; d < 256; d <<= 1) {
        int u = l[t];
        if (t >= d) u += l[t - d];
        __syncthreads();
        l[t] = u;
        __syncthreads();
    }
    const int gpos = cbase + l[t] - v;              // exclusive
    const int node = (b << 8) + t;
    if (node < N_NODES) offset[node] = gpos;
    cursor[t] = gpos;
    __syncthreads();

    for (int i = t; i < cnt; i += 256) {
        const int p = bpair[base + i];
        const int pos = atomicAdd(&cursor[p & 255], 1);
        csr[pos] = p >> 8;
    }
}

// ---------------------------------------------------------------------------
// Dual-stream gather: wave w aggregates nodes w and w+50000 with two
// independent 8-deep load pipelines.
// ---------------------------------------------------------------------------
#define GATHER8(S, ACC)                                                        \
    {                                                                          \
        const int t0 = __shfl(S, j + 0), t1 = __shfl(S, j + 1);                \
        const int t2 = __shfl(S, j + 2), t3 = __shfl(S, j + 3);                \
        const int t4 = __shfl(S, j + 4), t5 = __shfl(S, j + 5);                \
        const int t6 = __shfl(S, j + 6), t7 = __shfl(S, j + 7);                \
        const float u0 = (float)x[t0 * 64 + f], u1 = (float)x[t1 * 64 + f];    \
        const float u2 = (float)x[t2 * 64 + f], u3 = (float)x[t3 * 64 + f];    \
        const float u4 = (float)x[t4 * 64 + f], u5 = (float)x[t5 * 64 + f];    \
        const float u6 = (float)x[t6 * 64 + f], u7 = (float)x[t7 * 64 + f];    \
        ACC += ((u0 + u1) + (u2 + u3)) + ((u4 + u5) + (u6 + u7));              \
    }
#define GATHER4(S, J, ACC)                                                     \
    {                                                                          \
        const int t0 = __shfl(S, J + 0), t1 = __shfl(S, J + 1);                \
        const int t2 = __shfl(S, J + 2), t3 = __shfl(S, J + 3);                \
        const float u0 = (float)x[t0 * 64 + f], u1 = (float)x[t1 * 64 + f];    \
        const float u2 = (float)x[t2 * 64 + f], u3 = (float)x[t3 * 64 + f];    \
        ACC += (u0 + u1) + (u2 + u3);                                          \
    }

__global__ void agg2_kernel(const bf16_t* __restrict__ x,
                            const int* __restrict__ offset,
                            const int* __restrict__ csr,
                            bf16_t* __restrict__ hout) {
    const int w = (blockIdx.x * 256 + threadIdx.x) >> 6;   // 0..49999 (grid exact)
    const int f = threadIdx.x & 63;
    const int nA = w;
    const int nB = w + HALFN;

    const int oA = offset[nA], eA = offset[nA + 1];
    const int oB = offset[nB], eB = offset[nB + 1];
    const int dA = eA - oA, dB = eB - oB;

    float accA = (float)x[nA * 64 + f];
    float accB = (float)x[nB * 64 + f];

    for (int base = 0; base < dA || base < dB; base += 64) {
        const int ra = dA - base, rb2 = dB - base;
        const int cntA = ra <= 0 ? 0 : (ra < 64 ? ra : 64);
        const int cntB = rb2 <= 0 ? 0 : (rb2 < 64 ? rb2 : 64);
        int sA = 0, sB = 0;
        if (f < cntA) sA = csr[oA + base + f];
        if (f < cntB) sB = csr[oB + base + f];

        int j = 0;
        for (; j + 8 <= cntA && j + 8 <= cntB; j += 8) {
            GATHER8(sA, accA)
            GATHER8(sB, accB)
        }
        int jA = j, jB = j;
        for (; jA + 8 <= cntA; jA += 8) { const int j = jA; GATHER8(sA, accA) }
        for (; jB + 8 <= cntB; jB += 8) { const int j = jB; GATHER8(sB, accB) }
        if (jA + 4 <= cntA && jB + 4 <= cntB) {
            GATHER4(sA, jA, accA)
            GATHER4(sB, jB, accB)
            jA += 4; jB += 4;
        }
        if (jA + 4 <= cntA) { GATHER4(sA, jA, accA) jA += 4; }
        if (jB + 4 <= cntB) { GATHER4(sB, jB, accB) jB += 4; }
        for (; jA < cntA; ++jA) { const int t = __shfl(sA, jA); accA += (float)x[t * 64 + f]; }
        for (; jB < cntB; ++jB) { const int t = __shfl(sB, jB); accB += (float)x[t * 64 + f]; }
    }
    hout[nA * 64 + f] = (bf16_t)accA;
    hout[nB * 64 + f] = (bf16_t)accB;
}

// ---------------------------------------------------------------------------
// MLP: xout = bf16( relu( relu(hin @ wa + ba) @ wb + bb ) )
// 782 blocks, <=2 tiles each, next tile's A-frags prefetched during compute.
// POOL=1 (layer 3): segmented mean-pool numerator into gsum atomics.
// ---------------------------------------------------------------------------
template <int POOL>
__global__ void mlp_kernel(const bf16_t* __restrict__ hin,
                           const float* __restrict__ wa, const float* __restrict__ ba,
                           const float* __restrict__ wb, const float* __restrict__ bb,
                           bf16_t* __restrict__ xout,
                           const int* __restrict__ batch,
                           float* __restrict__ gsum) {
    __shared__ __align__(16) bf16_t wfrag[2][8][64][8];  // [mat][ct*2+ks][lane][j]
    __shared__ __align__(16) bf16_t hs[4][16][72];       // per-wave, reused h1/h2
    __shared__ float biasA[64], biasB[64];

    const int tid  = threadIdx.x;
    const int wv   = tid >> 6;
    const int lane = tid & 63;
    const int l15  = lane & 15;
    const int quad = lane >> 4;

    {
        const int k  = tid >> 2;
        const int n0 = (tid & 3) << 4;
        const int ks = k >> 5, qd = (k >> 3) & 3, jj = k & 7;
        const int fi = ((n0 >> 4) << 1) + ks;
#pragma unroll
        for (int m = 0; m < 2; ++m) {
            const float* w = m ? wb : wa;
            const f32x4 v0 = *(const f32x4*)(w + k * 64 + n0);
            const f32x4 v1 = *(const f32x4*)(w + k * 64 + n0 + 4);
            const f32x4 v2 = *(const f32x4*)(w + k * 64 + n0 + 8);
            const f32x4 v3 = *(const f32x4*)(w + k * 64 + n0 + 12);
#pragma unroll
            for (int l = 0; l < 4; ++l) {
                wfrag[m][fi][qd * 16 + l][jj]      = (bf16_t)v0[l];
                wfrag[m][fi][qd * 16 + 4 + l][jj]  = (bf16_t)v1[l];
                wfrag[m][fi][qd * 16 + 8 + l][jj]  = (bf16_t)v2[l];
                wfrag[m][fi][qd * 16 + 12 + l][jj] = (bf16_t)v3[l];
            }
        }
        if (tid < 64) biasA[tid] = ba[tid];
        else if (tid < 128) biasB[tid - 64] = bb[tid - 64];
    }
    __syncthreads();

    const int ntiles = (N_NODES + 63) / 64;   // 1563
    int tile = blockIdx.x;

    // load A-frags for first tile
    bf16x8 af[2];
    {
        const int rowa = tile * 64 + wv * 16 + l15;
        const int rowc = rowa < N_NODES ? rowa : N_NODES - 1;
#pragma unroll
        for (int ks = 0; ks < 2; ++ks)
            af[ks] = *(const bf16x8*)(hin + rowc * 64 + ks * 32 + quad * 8);
    }

    for (;;) {
        const int next = tile + gridDim.x;
        const bool has_next = next < ntiles;

        // prefetch next tile's A-frags (in flight during MFMA chain)
        bf16x8 afn[2];
        if (has_next) {
            const int rowa = next * 64 + wv * 16 + l15;
            const int rowc = rowa < N_NODES ? rowa : N_NODES - 1;
#pragma unroll
            for (int ks = 0; ks < 2; ++ks)
                afn[ks] = *(const bf16x8*)(hin + rowc * 64 + ks * 32 + quad * 8);
        }

        const int rb = tile * 64 + wv * 16;

        // GEMM1 -> relu -> hs
#pragma unroll
        for (int ct = 0; ct < 4; ++ct) {
            const bf16x8 b0 = *(const bf16x8*)&wfrag[0][ct * 2 + 0][lane][0];
            const bf16x8 b1 = *(const bf16x8*)&wfrag[0][ct * 2 + 1][lane][0];
            f32x4 acc = {0.f, 0.f, 0.f, 0.f};
            acc = __builtin_amdgcn_mfma_f32_16x16x32_bf16(af[0], b0, acc, 0, 0, 0);
            acc = __builtin_amdgcn_mfma_f32_16x16x32_bf16(af[1], b1, acc, 0, 0, 0);
            const float bv = biasA[ct * 16 + l15];
#pragma unroll
            for (int r = 0; r < 4; ++r) {
                float h = acc[r] + bv;
                h = h > 0.f ? h : 0.f;
                hs[wv][quad * 4 + r][ct * 16 + l15] = (bf16_t)h;
            }
        }

        bf16x8 a2[2];
#pragma unroll
        for (int ks = 0; ks < 2; ++ks)
            a2[ks] = *(const bf16x8*)(&hs[wv][l15][ks * 32 + quad * 8]);

        // GEMM2 -> relu -> hs
#pragma unroll
        for (int ct = 0; ct < 4; ++ct) {
            const bf16x8 b0 = *(const bf16x8*)&wfrag[1][ct * 2 + 0][lane][0];
            const bf16x8 b1 = *(const bf16x8*)&wfrag[1][ct * 2 + 1][lane][0];
            f32x4 acc = {0.f, 0.f, 0.f, 0.f};
            acc = __builtin_amdgcn_mfma_f32_16x16x32_bf16(a2[0], b0, acc, 0, 0, 0);
            acc = __builtin_amdgcn_mfma_f32_16x16x32_bf16(a2[1], b1, acc, 0, 0, 0);
            const float bv = biasB[ct * 16 + l15];
#pragma unroll
            for (int r = 0; r < 4; ++r) {
                float h = acc[r] + bv;
                h = h > 0.f ? h : 0.f;
                hs[wv][quad * 4 + r][ct * 16 + l15] = (bf16_t)h;
            }
        }

        if (POOL) {
            // segmented mean-pool numerator: ~1 atomic per graph run per wave
            int cur = -1;
            float acc = 0.f;
            for (int r = 0; r < 16; ++r) {
                const int row = rb + r;
                if (row >= N_NODES) break;
                const int g = batch[row];           // wave-uniform
                const float v = (float)hs[wv][r][lane];
                if (g != cur) {
                    if (cur >= 0) unsafeAtomicAdd(gsum + cur * 64 + lane, acc);
                    acc = 0.f;
                    cur = g;
                }
                acc += v;
            }
            if (cur >= 0) unsafeAtomicAdd(gsum + cur * 64 + lane, acc);
        } else {
            const int colg = (lane & 7) * 8;
#pragma unroll
            for (int sx = 0; sx < 2; ++sx) {
                const int r16 = (lane >> 3) + 8 * sx;
                const int grow = rb + r16;
                const bf16x8 v = *(const bf16x8*)&hs[wv][r16][colg];
                if (grow < N_NODES)
                    *(bf16x8*)(xout + grow * 64 + colg) = v;
            }
        }

        if (!has_next) break;
        af[0] = afn[0];
        af[1] = afn[1];
        tile = next;
    }
}

// out[g][c] = (gsum[g]/max(cnt,1)) . wc[:,c] + bc[c]; cnt via binary search
__global__ void cls_kernel(const float* __restrict__ gsum,
                           const int* __restrict__ batch,
                           const float* __restrict__ wc, const float* __restrict__ bc,
                           float* __restrict__ out) {
    const int g = blockIdx.x;
    const int c = threadIdx.x;
    if (c >= N_CLS) return;
    int lo = 0, hi = N_NODES;
    while (lo < hi) { const int m = (lo + hi) >> 1; if (batch[m] < g) lo = m + 1; else hi = m; }
    const int lb = lo;
    lo = 0; hi = N_NODES;
    while (lo < hi) { const int m = (lo + hi) >> 1; if (batch[m] <= g) lo = m + 1; else hi = m; }
    const int cnt = lo - lb;
    const float inv = 1.f / (float)(cnt > 1 ? cnt : 1);
    float acc = bc[c];
    for (int k = 0; k < 64; ++k)
        acc += gsum[g * 64 + k] * inv * wc[k * N_CLS + c];
    out[g * N_CLS + c] = acc;
}

// ---------------------------------------------------------------------------
extern "C" void kernel_launch(void* const* d_in, const int* in_sizes, int n_in,
                              void* d_out, int out_size, void* d_ws, size_t ws_size,
                              hipStream_t stream) {
    const float* x   = (const float*)d_in[0];
    const float* w1a = (const float*)d_in[1];
    const float* b1a = (const float*)d_in[2];
    const float* w1b = (const float*)d_in[3];
    const float* b1b = (const float*)d_in[4];
    const float* w2a = (const float*)d_in[5];
    const float* b2a = (const float*)d_in[6];
    const float* w2b = (const float*)d_in[7];
    const float* b2b = (const float*)d_in[8];
    const float* w3a = (const float*)d_in[9];
    const float* b3a = (const float*)d_in[10];
    const float* w3b = (const float*)d_in[11];
    const float* b3b = (const float*)d_in[12];
    const float* wc  = (const float*)d_in[13];
    const float* bc  = (const float*)d_in[14];
    const int*   ei    = (const int*)d_in[15];
    const int*   batch = (const int*)d_in[16];
    float* out = (float*)d_out;

    // workspace layout (~50.1 MB, 16B-aligned)
    char*   ws     = (char*)d_ws;
    int*    bcnt   = (int*)ws;                      // 391 ints (pad 1568)
    int*    offset = (int*)(ws + 3136);             // N+1 ints (pad 400016)
    int*    csr    = (int*)(ws + 403152);           // E ints = 4,800,000
    int*    bpair  = (int*)(ws + 5203152);          // 391*4096*4 = 6,406,144
    bf16_t* xbf    = (bf16_t*)(ws + 11609296);      // 12,800,000
    bf16_t* h      = (bf16_t*)(ws + 24409296);      // 12,800,000
    bf16_t* xA     = (bf16_t*)(ws + 37209296);      // 12,800,000
    float*  gsum   = (float*)(ws + 50009296);       // 32,768

    const int e4grid  = (N_EDGES / 4 + 255) / 256;  // 1172
    const int a2grid  = HALFN / 4;                  // 12500 (2 nodes/wave, exact)
    const int mlpgrid = 782;                        // <=2 tiles/block

    // x -> bf16 (+ zero bcnt/gsum)
    tobf_kernel<<<(N_NODES * 64) / (256 * 8), 256, 0, stream>>>(x, xbf, bcnt, gsum);

    // CSR build (once, reused 3x)
    binA_kernel<<<e4grid, 256, 0, stream>>>(ei, bcnt, bpair);
    sortfill_kernel<<<NBUCK, 256, 0, stream>>>(bpair, bcnt, offset, csr);

    // layer 1
    agg2_kernel<<<a2grid, 256, 0, stream>>>(xbf, offset, csr, h);
    mlp_kernel<0><<<mlpgrid, 256, 0, stream>>>(h, w1a, b1a, w1b, b1b, xA, nullptr, nullptr);
    // layer 2
    agg2_kernel<<<a2grid, 256, 0, stream>>>(xA, offset, csr, h);
    mlp_kernel<0><<<mlpgrid, 256, 0, stream>>>(h, w2a, b2a, w2b, b2b, xA, nullptr, nullptr);
    // layer 3 (fused pooling epilogue)
    agg2_kernel<<<a2grid, 256, 0, stream>>>(xA, offset, csr, h);
    mlp_kernel<1><<<mlpgrid, 256, 0, stream>>>(h, w3a, b3a, w3b, b3b, nullptr, batch, gsum);

    // classify
    cls_kernel<<<N_GRAPH, 64, 0, stream>>>(gsum, batch, wc, bc, out);
}